// Round 2
// baseline (721.201 us; speedup 1.0000x reference)
//
#include <hip/hip_runtime.h>
#include <math.h>

#define BB 16
#define LL 2048
#define SSZ 2048
#define EE 64
#define FF 7
#define DD 448

// ws offsets (in floats)
#define OFF_QT 0                         // B*L*E = 2097152
#define OFF_KT 2097152                   // B*S*E = 2097152
#define OFF_QF 4194304                   // B*E*7 = 7168
#define OFF_KF 4201472                   // 7168
#define OFF_VS 4208640                   // B*E = 1024
#define OFF_AF 4209664                   // B*7 = 112
#define OFF_CM 4209776                   // B*S = 32768 (col max)
#define OFF_CZ 4242544                   // B*S = 32768 (col 1/Z)
#define OFF_AT 4275312                   // B*L = 32768 (rowsum)
#define OFF_MS 4308080                   // 2*B = 32 (M, 1/S per batch)

// ---------- reduce q or k: t_out[b,l,e] = sum_r src; f_out[b,e,r] += sum_l src ----------
__global__ __launch_bounds__(256) void k_reduce_qk(const float* __restrict__ src,
                                                   float* __restrict__ t_out,
                                                   float* __restrict__ f_out) {
    __shared__ float buf[16 * DD];                   // 28 KB
    int blk = blockIdx.x;
    int b = blk >> 7;                                 // 128 blocks per batch (L/16)
    int l0 = (blk & 127) << 4;
    const float4* s4 = (const float4*)(src + ((size_t)b * LL + l0) * DD);
    float4* b4 = (float4*)buf;
#pragma unroll
    for (int i = 0; i < 7; i++) b4[threadIdx.x + 256 * i] = s4[threadIdx.x + 256 * i];
    __syncthreads();
    int e = threadIdx.x & 63, g = threadIdx.x >> 6;
    float fa[7] = {0.f, 0.f, 0.f, 0.f, 0.f, 0.f, 0.f};
    for (int rr = g; rr < 16; rr += 4) {
        float s = 0.f;
#pragma unroll
        for (int r = 0; r < 7; r++) { float v = buf[rr * DD + e * 7 + r]; s += v; fa[r] += v; }
        t_out[((size_t)b * LL + l0 + rr) * EE + e] = s;
    }
    __syncthreads();
#pragma unroll
    for (int r = 0; r < 7; r++) buf[(g * 64 + e) * 7 + r] = fa[r];
    __syncthreads();
    if (g == 0) {
#pragma unroll
        for (int r = 0; r < 7; r++) {
            float s = buf[e * 7 + r] + buf[(64 + e) * 7 + r] + buf[(128 + e) * 7 + r] + buf[(192 + e) * 7 + r];
            atomicAdd(&f_out[(b * EE + e) * 7 + r], s);
        }
    }
}

// ---------- reduce v: vs[b,e] += sum_{l,r} src ----------
__global__ __launch_bounds__(256) void k_reduce_v(const float* __restrict__ src,
                                                  float* __restrict__ vs) {
    __shared__ float buf[16 * DD];
    int blk = blockIdx.x;
    int b = blk >> 7;
    int l0 = (blk & 127) << 4;
    const float4* s4 = (const float4*)(src + ((size_t)b * LL + l0) * DD);
    float4* b4 = (float4*)buf;
#pragma unroll
    for (int i = 0; i < 7; i++) b4[threadIdx.x + 256 * i] = s4[threadIdx.x + 256 * i];
    __syncthreads();
    int e = threadIdx.x & 63, g = threadIdx.x >> 6;
    float a = 0.f;
    for (int rr = g; rr < 16; rr += 4) {
#pragma unroll
        for (int r = 0; r < 7; r++) a += buf[rr * DD + e * 7 + r];
    }
    __syncthreads();
    buf[g * 64 + e] = a;
    __syncthreads();
    if (g == 0) atomicAdd(&vs[b * EE + e], buf[e] + buf[64 + e] + buf[128 + e] + buf[192 + e]);
}

// ---------- feature softmax: af[b,r] = sum_p softmax_r(qf^T kf)[r,p] ----------
__global__ void k_feat(const float* __restrict__ qf, const float* __restrict__ kf,
                       float* __restrict__ af) {
    __shared__ float qs[448], ks[448], sf[49], A[49];
    int b = blockIdx.x, t = threadIdx.x;
    for (int i = t; i < 448; i += 64) { qs[i] = qf[b * 448 + i]; ks[i] = kf[b * 448 + i]; }
    __syncthreads();
    if (t < 49) {
        int r = t / 7, p = t % 7;
        float s = 0.f;
        for (int e = 0; e < 64; e++) s += qs[e * 7 + r] * ks[e * 7 + p];
        sf[t] = s;
    }
    __syncthreads();
    if (t < 7) {  // column p = t: softmax over r
        float m = -1e30f;
        for (int r = 0; r < 7; r++) m = fmaxf(m, sf[r * 7 + t]);
        float z = 0.f;
        for (int r = 0; r < 7; r++) z += __expf(sf[r * 7 + t] - m);
        float iz = 1.f / z;
        for (int r = 0; r < 7; r++) A[r * 7 + t] = __expf(sf[r * 7 + t] - m) * iz;
    }
    __syncthreads();
    if (t < 7) {
        float s = 0.f;
        for (int p = 0; p < 7; p++) s += A[t * 7 + p];
        af[b * 7 + t] = s;
    }
}

// ---------- pass A: per column s, online max & sumexp over all l ----------
__global__ __launch_bounds__(256) void k_colstats(const float* __restrict__ qt,
                                                  const float* __restrict__ kt,
                                                  float* __restrict__ cm,
                                                  float* __restrict__ cz) {
    __shared__ float kT[64 * 129];  // [e][c], c = 0..127   (33.0 KB)
    __shared__ float qb[64 * 65];   // [r][e]               (16.6 KB)
    int b = blockIdx.x >> 4;
    int c0 = (blockIdx.x & 15) << 7;
    int tid = threadIdx.x;
    int tc = tid & 15, tr = tid >> 4;
    // load k tile once (128 cols x 64 e)
    for (int idx = tid; idx < 128 * 16; idx += 256) {
        int c = idx >> 4, e4 = (idx & 15) << 2;
        float4 v = *(const float4*)(kt + ((size_t)b * SSZ + c0 + c) * EE + e4);
        kT[(e4 + 0) * 129 + c] = v.x;
        kT[(e4 + 1) * 129 + c] = v.y;
        kT[(e4 + 2) * 129 + c] = v.z;
        kT[(e4 + 3) * 129 + c] = v.w;
    }
    float m[8], s[8];
#pragma unroll
    for (int j = 0; j < 8; j++) { m[j] = -1e30f; s[j] = 0.f; }
    for (int lt = 0; lt < 32; lt++) {
        __syncthreads();
        for (int idx = tid; idx < 64 * 16; idx += 256) {
            int r = idx >> 4, e4 = (idx & 15) << 2;
            float4 v = *(const float4*)(qt + ((size_t)b * LL + lt * 64 + r) * EE + e4);
            qb[r * 65 + e4 + 0] = v.x;
            qb[r * 65 + e4 + 1] = v.y;
            qb[r * 65 + e4 + 2] = v.z;
            qb[r * 65 + e4 + 3] = v.w;
        }
        __syncthreads();
        float acc[4][8];
#pragma unroll
        for (int i = 0; i < 4; i++)
#pragma unroll
            for (int j = 0; j < 8; j++) acc[i][j] = 0.f;
#pragma unroll 4
        for (int e = 0; e < 64; e++) {
            float qv[4], kv[8];
#pragma unroll
            for (int i = 0; i < 4; i++) qv[i] = qb[(i * 16 + tr) * 65 + e];
#pragma unroll
            for (int j = 0; j < 8; j++) kv[j] = kT[e * 129 + j * 16 + tc];
#pragma unroll
            for (int i = 0; i < 4; i++)
#pragma unroll
                for (int j = 0; j < 8; j++) acc[i][j] += qv[i] * kv[j];
        }
#pragma unroll
        for (int j = 0; j < 8; j++) {
            float tm = fmaxf(fmaxf(acc[0][j], acc[1][j]), fmaxf(acc[2][j], acc[3][j]));
            if (tm > m[j]) { s[j] *= __expf(m[j] - tm); m[j] = tm; }
#pragma unroll
            for (int i = 0; i < 4; i++) s[j] += __expf(acc[i][j] - m[j]);
        }
    }
    __syncthreads();
    float* mred = qb;   // [16][128]
    float* sred = kT;   // [16][128]
#pragma unroll
    for (int j = 0; j < 8; j++) {
        mred[tr * 128 + j * 16 + tc] = m[j];
        sred[tr * 128 + j * 16 + tc] = s[j];
    }
    __syncthreads();
    if (tid < 128) {
        float M = -1e30f, Z = 0.f;
        for (int g = 0; g < 16; g++) {
            float mg = mred[g * 128 + tid], sg = sred[g * 128 + tid];
            float nm = fmaxf(M, mg);
            Z = Z * __expf(M - nm) + sg * __expf(mg - nm);
            M = nm;
        }
        cm[(size_t)b * SSZ + c0 + tid] = M;
        cz[(size_t)b * SSZ + c0 + tid] = 1.f / Z;
    }
}

// ---------- pass B: rowsum[b,l] = sum_s exp(score - m_s) * invZ_s ----------
__global__ __launch_bounds__(256) void k_rowsum(const float* __restrict__ qt,
                                                const float* __restrict__ kt,
                                                const float* __restrict__ cm,
                                                const float* __restrict__ cz,
                                                float* __restrict__ at) {
    __shared__ float qT[64 * 129];  // [e][r], r = 0..127
    __shared__ float kb[64 * 65];   // [c][e]
    __shared__ float mt[64], zt[64];
    int b = blockIdx.x >> 4;
    int l0 = (blockIdx.x & 15) << 7;
    int tid = threadIdx.x;
    int tl = tid & 15, tg = tid >> 4;
    // load q tile once (128 rows x 64 e), transposed
    for (int idx = tid; idx < 128 * 16; idx += 256) {
        int r = idx >> 4, e4 = (idx & 15) << 2;
        float4 v = *(const float4*)(qt + ((size_t)b * LL + l0 + r) * EE + e4);
        qT[(e4 + 0) * 129 + r] = v.x;
        qT[(e4 + 1) * 129 + r] = v.y;
        qT[(e4 + 2) * 129 + r] = v.z;
        qT[(e4 + 3) * 129 + r] = v.w;
    }
    float rs[8] = {0.f, 0.f, 0.f, 0.f, 0.f, 0.f, 0.f, 0.f};
    for (int st = 0; st < 32; st++) {
        __syncthreads();
        for (int idx = tid; idx < 64 * 16; idx += 256) {
            int c = idx >> 4, e4 = (idx & 15) << 2;
            float4 v = *(const float4*)(kt + ((size_t)b * SSZ + st * 64 + c) * EE + e4);
            kb[c * 65 + e4 + 0] = v.x;
            kb[c * 65 + e4 + 1] = v.y;
            kb[c * 65 + e4 + 2] = v.z;
            kb[c * 65 + e4 + 3] = v.w;
        }
        if (tid < 64) {
            mt[tid] = cm[(size_t)b * SSZ + st * 64 + tid];
            zt[tid] = cz[(size_t)b * SSZ + st * 64 + tid];
        }
        __syncthreads();
        float acc[8][4];
#pragma unroll
        for (int j = 0; j < 8; j++)
#pragma unroll
            for (int i = 0; i < 4; i++) acc[j][i] = 0.f;
#pragma unroll 4
        for (int e = 0; e < 64; e++) {
            float qv[8], kv[4];
#pragma unroll
            for (int j = 0; j < 8; j++) qv[j] = qT[e * 129 + j * 16 + tl];
#pragma unroll
            for (int i = 0; i < 4; i++) kv[i] = kb[(i * 16 + tg) * 65 + e];
#pragma unroll
            for (int j = 0; j < 8; j++)
#pragma unroll
                for (int i = 0; i < 4; i++) acc[j][i] += qv[j] * kv[i];
        }
#pragma unroll
        for (int j = 0; j < 8; j++)
#pragma unroll
            for (int i = 0; i < 4; i++) {
                int c = i * 16 + tg;
                rs[j] += __expf(acc[j][i] - mt[c]) * zt[c];
            }
    }
    __syncthreads();
    float* red = qT;  // [16][128]
#pragma unroll
    for (int j = 0; j < 8; j++) red[tg * 128 + j * 16 + tl] = rs[j];
    __syncthreads();
    if (tid < 128) {
        float s = 0.f;
        for (int g = 0; g < 16; g++) s += red[g * 128 + tid];
        at[(size_t)b * LL + l0 + tid] = s;
    }
}

// ---------- per-batch softmax stats over A_tf = at[l]*af[r] (both > 0) ----------
__global__ __launch_bounds__(256) void k_batchstats(const float* __restrict__ at,
                                                    const float* __restrict__ af,
                                                    float* __restrict__ ms) {
    __shared__ float red[256];
    __shared__ float afs[7];
    int b = blockIdx.x, t = threadIdx.x;
    if (t < 7) afs[t] = af[b * 7 + t];
    float mx = -1e30f;
    for (int l = t; l < LL; l += 256) mx = fmaxf(mx, at[(size_t)b * LL + l]);
    red[t] = mx;
    __syncthreads();
    for (int o = 128; o > 0; o >>= 1) {
        if (t < o) red[t] = fmaxf(red[t], red[t + o]);
        __syncthreads();
    }
    float mxat = red[0];
    __syncthreads();
    float mxaf = afs[0];
#pragma unroll
    for (int r = 1; r < 7; r++) mxaf = fmaxf(mxaf, afs[r]);
    float M = mxat * mxaf;  // valid: at>0, af>0
    float s = 0.f;
    for (int l = t; l < LL; l += 256) {
        float a = at[(size_t)b * LL + l];
#pragma unroll
        for (int r = 0; r < 7; r++) s += __expf(a * afs[r] - M);
    }
    red[t] = s;
    __syncthreads();
    for (int o = 128; o > 0; o >>= 1) {
        if (t < o) red[t] += red[t + o];
        __syncthreads();
    }
    if (t == 0) { ms[b * 2] = M; ms[b * 2 + 1] = 1.f / red[0]; }
}

// ---------- output: out[b,l,e*7+r] = exp(at*af - M)*invS * v_sum[b,e] ----------
__global__ __launch_bounds__(256) void k_out(const float* __restrict__ at,
                                             const float* __restrict__ af,
                                             const float* __restrict__ vs,
                                             const float* __restrict__ ms,
                                             float* __restrict__ out) {
    int row = blockIdx.x * 4 + (threadIdx.x >> 6);  // row = b*L + l
    int e = threadIdx.x & 63;
    int b = row >> 11;
    float a = at[row];
    float M = ms[b * 2], iS = ms[b * 2 + 1];
    float v = vs[b * EE + e];
    float* o = out + (size_t)row * DD + e * 7;
#pragma unroll
    for (int r = 0; r < 7; r++) o[r] = __expf(a * af[b * 7 + r] - M) * iS * v;
}

extern "C" void kernel_launch(void* const* d_in, const int* in_sizes, int n_in,
                              void* d_out, int out_size, void* d_ws, size_t ws_size,
                              hipStream_t stream) {
    const float* q = (const float*)d_in[0];
    const float* k = (const float*)d_in[1];
    const float* v = (const float*)d_in[2];
    float* out = (float*)d_out;
    float* ws = (float*)d_ws;

    float* qt = ws + OFF_QT;
    float* kt = ws + OFF_KT;
    float* qf = ws + OFF_QF;
    float* kf = ws + OFF_KF;
    float* vs = ws + OFF_VS;
    float* af = ws + OFF_AF;
    float* cm = ws + OFF_CM;
    float* cz = ws + OFF_CZ;
    float* at = ws + OFF_AT;
    float* ms = ws + OFF_MS;

    // zero the atomic accumulators (qf, kf, vs are contiguous)
    hipMemsetAsync(qf, 0, (7168 + 7168 + 1024) * sizeof(float), stream);

    k_reduce_qk<<<2048, 256, 0, stream>>>(q, qt, qf);
    k_reduce_qk<<<2048, 256, 0, stream>>>(k, kt, kf);
    k_reduce_v<<<2048, 256, 0, stream>>>(v, vs);
    k_feat<<<16, 64, 0, stream>>>(qf, kf, af);
    k_colstats<<<256, 256, 0, stream>>>(qt, kt, cm, cz);
    k_rowsum<<<256, 256, 0, stream>>>(qt, kt, cm, cz, at);
    k_batchstats<<<16, 256, 0, stream>>>(at, af, ms);
    k_out<<<8192, 256, 0, stream>>>(at, af, vs, ms, out);
}

// Round 5
// 545.647 us; speedup vs baseline: 1.3217x; 1.3217x over previous
//
#include <hip/hip_runtime.h>
#include <math.h>

#define LL 2048
#define EE 64
#define FF 7
#define DD 448

// ws offsets (floats)
#define OFF_QT 0                         // 16*2048*64 = 2097152
#define OFF_KT 2097152                   // 2097152
#define OFF_QF 4194304                   // 16*64*7 = 7168
#define OFF_KF 4201472                   // 7168
#define OFF_VS 4208640                   // 16*64 = 1024
#define OFF_AF 4209664                   // 16*7 = 112
#define OFF_CM 4209776                   // 16*2048 = 32768
#define OFF_CZ 4242544                   // 32768
#define OFF_AT 4275312                   // 32768
#define OFF_MS 4308080                   // 32
#define OFF_CMP 4308112                  // 16*8*2048 = 262144 (partial col max)
#define OFF_CZP 4570256                  // 262144 (partial col sumexp)
// end: 4832400 floats = 19.3 MB

// ---------- reduce q or k: t_out[b,l,e] = sum_r src; f_out[b,e,r] += sum_l src ----------
__global__ __launch_bounds__(256) void k_reduce_qk(const float* __restrict__ src,
                                                   float* __restrict__ t_out,
                                                   float* __restrict__ f_out) {
    __shared__ float buf[16 * DD];
    int blk = blockIdx.x;
    int b = blk >> 7;
    int l0 = (blk & 127) << 4;
    const float4* s4 = (const float4*)(src + ((size_t)b * LL + l0) * DD);
    float4* b4 = (float4*)buf;
#pragma unroll
    for (int i = 0; i < 7; i++) b4[threadIdx.x + 256 * i] = s4[threadIdx.x + 256 * i];
    __syncthreads();
    int e = threadIdx.x & 63, g = threadIdx.x >> 6;
    float fa[7] = {0.f, 0.f, 0.f, 0.f, 0.f, 0.f, 0.f};
    for (int rr = g; rr < 16; rr += 4) {
        float s = 0.f;
#pragma unroll
        for (int r = 0; r < 7; r++) { float v = buf[rr * DD + e * 7 + r]; s += v; fa[r] += v; }
        t_out[((size_t)b * LL + l0 + rr) * EE + e] = s;
    }
    __syncthreads();
#pragma unroll
    for (int r = 0; r < 7; r++) buf[(g * 64 + e) * 7 + r] = fa[r];
    __syncthreads();
    if (g == 0) {
#pragma unroll
        for (int r = 0; r < 7; r++) {
            float s = buf[e * 7 + r] + buf[(64 + e) * 7 + r] + buf[(128 + e) * 7 + r] + buf[(192 + e) * 7 + r];
            atomicAdd(&f_out[(b * EE + e) * 7 + r], s);
        }
    }
}

// ---------- reduce v: vs[b,e] += sum_{l,r} src ----------
__global__ __launch_bounds__(256) void k_reduce_v(const float* __restrict__ src,
                                                  float* __restrict__ vs) {
    __shared__ float buf[16 * DD];
    int blk = blockIdx.x;
    int b = blk >> 7;
    int l0 = (blk & 127) << 4;
    const float4* s4 = (const float4*)(src + ((size_t)b * LL + l0) * DD);
    float4* b4 = (float4*)buf;
#pragma unroll
    for (int i = 0; i < 7; i++) b4[threadIdx.x + 256 * i] = s4[threadIdx.x + 256 * i];
    __syncthreads();
    int e = threadIdx.x & 63, g = threadIdx.x >> 6;
    float a = 0.f;
    for (int rr = g; rr < 16; rr += 4) {
#pragma unroll
        for (int r = 0; r < 7; r++) a += buf[rr * DD + e * 7 + r];
    }
    __syncthreads();
    buf[g * 64 + e] = a;
    __syncthreads();
    if (g == 0) atomicAdd(&vs[b * EE + e], buf[e] + buf[64 + e] + buf[128 + e] + buf[192 + e]);
}

// ---------- feature softmax: af[b,r] = sum_p softmax_r(qf^T kf)[r,p] ----------
__global__ void k_feat(const float* __restrict__ qf, const float* __restrict__ kf,
                       float* __restrict__ af) {
    __shared__ float qs[448], ks[448], sf[49], A[49];
    int b = blockIdx.x, t = threadIdx.x;
    for (int i = t; i < 448; i += 64) { qs[i] = qf[b * 448 + i]; ks[i] = kf[b * 448 + i]; }
    __syncthreads();
    if (t < 49) {
        int r = t / 7, p = t % 7;
        float s = 0.f;
        for (int e = 0; e < 64; e++) s += qs[e * 7 + r] * ks[e * 7 + p];
        sf[t] = s;
    }
    __syncthreads();
    if (t < 7) {
        float m = -1e30f;
        for (int r = 0; r < 7; r++) m = fmaxf(m, sf[r * 7 + t]);
        float z = 0.f;
        for (int r = 0; r < 7; r++) z += __expf(sf[r * 7 + t] - m);
        float iz = 1.f / z;
        for (int r = 0; r < 7; r++) A[r * 7 + t] = __expf(sf[r * 7 + t] - m) * iz;
    }
    __syncthreads();
    if (t < 7) {
        float s = 0.f;
        for (int p = 0; p < 7; p++) s += A[t * 7 + p];
        af[b * 7 + t] = s;
    }
}

// ---------- pass A (partial): cols c0..c0+127, rows lbase..lbase+255 ----------
__global__ __launch_bounds__(256) void k_colstats(const float* __restrict__ qt,
                                                  const float* __restrict__ kt,
                                                  float* __restrict__ cmp,
                                                  float* __restrict__ czp) {
    __shared__ __align__(16) float kb[128 * 68];  // [c][e]  34.8 KB
    __shared__ __align__(16) float qb[64 * 68];   // [r][e]  17.4 KB
    int bid = blockIdx.x;
    int b = bid >> 7, cc = (bid >> 3) & 15, lc = bid & 7;
    int c0 = cc << 7, lbase = lc << 8;
    int tid = threadIdx.x, tc = tid & 15, tr = tid >> 4;
    for (int idx = tid; idx < 2048; idx += 256) {
        int c = idx >> 4, e4 = (idx & 15) << 2;
        *(float4*)(kb + c * 68 + e4) =
            *(const float4*)(kt + ((size_t)(b * LL + c0 + c)) * EE + e4);
    }
    float m[8], s[8];
#pragma unroll
    for (int j = 0; j < 8; j++) { m[j] = -1e30f; s[j] = 0.f; }
    for (int lt = 0; lt < 4; lt++) {
        __syncthreads();
        for (int idx = tid; idx < 1024; idx += 256) {
            int r = idx >> 4, e4 = (idx & 15) << 2;
            *(float4*)(qb + r * 68 + e4) =
                *(const float4*)(qt + ((size_t)(b * LL + lbase + lt * 64 + r)) * EE + e4);
        }
        __syncthreads();
        float acc[4][8];
#pragma unroll
        for (int i = 0; i < 4; i++)
#pragma unroll
            for (int j = 0; j < 8; j++) acc[i][j] = 0.f;
#pragma unroll
        for (int e = 0; e < 64; e += 4) {
            float4 qv[4], kv[8];
#pragma unroll
            for (int i = 0; i < 4; i++) qv[i] = *(const float4*)(qb + (i * 16 + tr) * 68 + e);
#pragma unroll
            for (int j = 0; j < 8; j++) kv[j] = *(const float4*)(kb + (j * 16 + tc) * 68 + e);
#pragma unroll
            for (int i = 0; i < 4; i++)
#pragma unroll
                for (int j = 0; j < 8; j++) {
                    acc[i][j] += qv[i].x * kv[j].x;
                    acc[i][j] += qv[i].y * kv[j].y;
                    acc[i][j] += qv[i].z * kv[j].z;
                    acc[i][j] += qv[i].w * kv[j].w;
                }
        }
#pragma unroll
        for (int j = 0; j < 8; j++) {
            float tm = fmaxf(fmaxf(acc[0][j], acc[1][j]), fmaxf(acc[2][j], acc[3][j]));
            if (tm > m[j]) { s[j] *= __expf(m[j] - tm); m[j] = tm; }
#pragma unroll
            for (int i = 0; i < 4; i++) s[j] += __expf(acc[i][j] - m[j]);
        }
    }
    __syncthreads();
    float* mred = kb;          // [16][128]
    float* sred = kb + 2048;   // [16][128]
#pragma unroll
    for (int j = 0; j < 8; j++) {
        mred[tr * 128 + j * 16 + tc] = m[j];
        sred[tr * 128 + j * 16 + tc] = s[j];
    }
    __syncthreads();
    if (tid < 128) {
        float M = -1e30f, Z = 0.f;
        for (int g = 0; g < 16; g++) {
            float mg = mred[g * 128 + tid], sg = sred[g * 128 + tid];
            float nm = fmaxf(M, mg);
            Z = Z * __expf(M - nm) + sg * __expf(mg - nm);
            M = nm;
        }
        cmp[((size_t)(b * 8 + lc)) * LL + c0 + tid] = M;
        czp[((size_t)(b * 8 + lc)) * LL + c0 + tid] = Z;
    }
}

// ---------- merge 8 partial col stats ----------
__global__ __launch_bounds__(256) void k_colmerge(const float* __restrict__ cmp,
                                                  const float* __restrict__ czp,
                                                  float* __restrict__ cm,
                                                  float* __restrict__ cz) {
    int idx = blockIdx.x * 256 + threadIdx.x;  // 0..32767
    int b = idx >> 11, s = idx & 2047;
    float mp[8], zp[8];
#pragma unroll
    for (int lc = 0; lc < 8; lc++) {
        mp[lc] = cmp[((size_t)(b * 8 + lc)) * LL + s];
        zp[lc] = czp[((size_t)(b * 8 + lc)) * LL + s];
    }
    float M = mp[0];
#pragma unroll
    for (int lc = 1; lc < 8; lc++) M = fmaxf(M, mp[lc]);
    float Z = 0.f;
#pragma unroll
    for (int lc = 0; lc < 8; lc++) Z += zp[lc] * __expf(mp[lc] - M);
    cm[idx] = M;
    cz[idx] = 1.f / Z;
}

// ---------- pass B (partial): rows l0..l0+127, cols sbase..sbase+255 -> atomicAdd at ----------
__global__ __launch_bounds__(256) void k_rowsum(const float* __restrict__ qt,
                                                const float* __restrict__ kt,
                                                const float* __restrict__ cm,
                                                const float* __restrict__ cz,
                                                float* __restrict__ at) {
    __shared__ __align__(16) float qb[128 * 68];  // [r][e]
    __shared__ __align__(16) float kb[64 * 68];   // [c][e]
    __shared__ float mt[64], zt[64];
    int bid = blockIdx.x;
    int b = bid >> 7, rc = (bid >> 3) & 15, sc = bid & 7;
    int l0 = rc << 7, sbase = sc << 8;
    int tid = threadIdx.x, tl = tid & 15, tg = tid >> 4;
    for (int idx = tid; idx < 2048; idx += 256) {
        int r = idx >> 4, e4 = (idx & 15) << 2;
        *(float4*)(qb + r * 68 + e4) =
            *(const float4*)(qt + ((size_t)(b * LL + l0 + r)) * EE + e4);
    }
    float rs[8] = {0.f, 0.f, 0.f, 0.f, 0.f, 0.f, 0.f, 0.f};
    for (int st = 0; st < 4; st++) {
        __syncthreads();
        for (int idx = tid; idx < 1024; idx += 256) {
            int c = idx >> 4, e4 = (idx & 15) << 2;
            *(float4*)(kb + c * 68 + e4) =
                *(const float4*)(kt + ((size_t)(b * LL + sbase + st * 64 + c)) * EE + e4);
        }
        if (tid < 64) {
            mt[tid] = cm[b * LL + sbase + st * 64 + tid];
            zt[tid] = cz[b * LL + sbase + st * 64 + tid];
        }
        __syncthreads();
        float acc[8][4];
#pragma unroll
        for (int j = 0; j < 8; j++)
#pragma unroll
            for (int i = 0; i < 4; i++) acc[j][i] = 0.f;
#pragma unroll
        for (int e = 0; e < 64; e += 4) {
            float4 qv[8], kv[4];
#pragma unroll
            for (int j = 0; j < 8; j++) qv[j] = *(const float4*)(qb + (j * 16 + tl) * 68 + e);
#pragma unroll
            for (int i = 0; i < 4; i++) kv[i] = *(const float4*)(kb + (i * 16 + tg) * 68 + e);
#pragma unroll
            for (int j = 0; j < 8; j++)
#pragma unroll
                for (int i = 0; i < 4; i++) {
                    acc[j][i] += qv[j].x * kv[i].x;
                    acc[j][i] += qv[j].y * kv[i].y;
                    acc[j][i] += qv[j].z * kv[i].z;
                    acc[j][i] += qv[j].w * kv[i].w;
                }
        }
#pragma unroll
        for (int j = 0; j < 8; j++)
#pragma unroll
            for (int i = 0; i < 4; i++) {
                int c = i * 16 + tg;
                rs[j] += __expf(acc[j][i] - mt[c]) * zt[c];
            }
    }
    __syncthreads();
    float* red = qb;  // [16][128]
#pragma unroll
    for (int j = 0; j < 8; j++) red[tg * 128 + j * 16 + tl] = rs[j];
    __syncthreads();
    if (tid < 128) {
        float ssum = 0.f;
        for (int g = 0; g < 16; g++) ssum += red[g * 128 + tid];
        atomicAdd(at + (size_t)b * LL + l0 + tid, ssum);
    }
}

// ---------- per-batch softmax stats over A_tf = at[l]*af[r] ----------
__global__ __launch_bounds__(256) void k_batchstats(const float* __restrict__ at,
                                                    const float* __restrict__ af,
                                                    float* __restrict__ ms) {
    __shared__ float red[256];
    __shared__ float afs[7];
    int b = blockIdx.x, t = threadIdx.x;
    if (t < 7) afs[t] = af[b * 7 + t];
    float mx = -1e30f;
    for (int l = t; l < LL; l += 256) mx = fmaxf(mx, at[(size_t)b * LL + l]);
    red[t] = mx;
    __syncthreads();
    for (int o = 128; o > 0; o >>= 1) {
        if (t < o) red[t] = fmaxf(red[t], red[t + o]);
        __syncthreads();
    }
    float mxat = red[0];
    __syncthreads();
    float mxaf = afs[0];
#pragma unroll
    for (int r = 1; r < 7; r++) mxaf = fmaxf(mxaf, afs[r]);
    float M = mxat * mxaf;  // valid: at>0, af>0
    float s = 0.f;
    for (int l = t; l < LL; l += 256) {
        float a = at[(size_t)b * LL + l];
#pragma unroll
        for (int r = 0; r < 7; r++) s += __expf(a * afs[r] - M);
    }
    red[t] = s;
    __syncthreads();
    for (int o = 128; o > 0; o >>= 1) {
        if (t < o) red[t] += red[t + o];
        __syncthreads();
    }
    if (t == 0) { ms[b * 2] = M; ms[b * 2 + 1] = 1.f / red[0]; }
}

// ---------- output via LDS staging, coalesced float4 stores ----------
__global__ __launch_bounds__(256) void k_out(const float* __restrict__ at,
                                             const float* __restrict__ af,
                                             const float* __restrict__ vs,
                                             const float* __restrict__ ms,
                                             float* __restrict__ out) {
    __shared__ __align__(16) float sm[4 * DD];
    int row0 = blockIdx.x << 2;
    int tid = threadIdx.x;
    int g = tid >> 6, e = tid & 63;
    int row = row0 + g;
    int b = row >> 11;
    float a = at[row];
    float M = ms[b * 2], iS = ms[b * 2 + 1];
    float v = vs[b * EE + e] * iS;
#pragma unroll
    for (int r = 0; r < 7; r++) sm[g * DD + e * 7 + r] = __expf(a * af[b * 7 + r] - M) * v;
    __syncthreads();
    float4* o4 = (float4*)(out + (size_t)row0 * DD);
    const float4* s4 = (const float4*)sm;
    for (int i = tid; i < 448; i += 256) o4[i] = s4[i];
}

extern "C" void kernel_launch(void* const* d_in, const int* in_sizes, int n_in,
                              void* d_out, int out_size, void* d_ws, size_t ws_size,
                              hipStream_t stream) {
    const float* q = (const float*)d_in[0];
    const float* k = (const float*)d_in[1];
    const float* v = (const float*)d_in[2];
    float* out = (float*)d_out;
    float* ws = (float*)d_ws;

    float* qt = ws + OFF_QT;
    float* kt = ws + OFF_KT;
    float* qf = ws + OFF_QF;
    float* kf = ws + OFF_KF;
    float* vs = ws + OFF_VS;
    float* af = ws + OFF_AF;
    float* cm = ws + OFF_CM;
    float* cz = ws + OFF_CZ;
    float* at = ws + OFF_AT;
    float* ms = ws + OFF_MS;
    float* cmp = ws + OFF_CMP;
    float* czp = ws + OFF_CZP;

    // zero the atomic accumulators: qf/kf/vs (contiguous) and at
    hipMemsetAsync(qf, 0, (7168 + 7168 + 1024) * sizeof(float), stream);
    hipMemsetAsync(at, 0, 32768 * sizeof(float), stream);

    k_reduce_qk<<<2048, 256, 0, stream>>>(q, qt, qf);
    k_reduce_qk<<<2048, 256, 0, stream>>>(k, kt, kf);
    k_reduce_v<<<2048, 256, 0, stream>>>(v, vs);
    k_feat<<<16, 64, 0, stream>>>(qf, kf, af);
    k_colstats<<<2048, 256, 0, stream>>>(qt, kt, cmp, czp);
    k_colmerge<<<128, 256, 0, stream>>>(cmp, czp, cm, cz);
    k_rowsum<<<2048, 256, 0, stream>>>(qt, kt, cm, cz, at);
    k_batchstats<<<16, 256, 0, stream>>>(at, af, ms);
    k_out<<<8192, 256, 0, stream>>>(at, af, vs, ms, out);
}

// Round 6
// 498.185 us; speedup vs baseline: 1.4477x; 1.0953x over previous
//
#include <hip/hip_runtime.h>
#include <math.h>

#define LL 2048
#define EE 64
#define FF 7
#define DD 448

// ws offsets (floats) — 4,308,112 floats = 17.2 MB total
#define OFF_QT 0                         // 16*2048*64 = 2097152
#define OFF_KT 2097152                   // 2097152
#define OFF_QF 4194304                   // 16*64*7 = 7168
#define OFF_KF 4201472                   // 7168
#define OFF_VS 4208640                   // 16*64 = 1024
#define OFF_AF 4209664                   // 16*7 = 112
#define OFF_CM 4209776                   // 16*2048 = 32768
#define OFF_CZ 4242544                   // 32768
#define OFF_AT 4275312                   // 32768
#define OFF_MS 4308080                   // 32
// cmp/czp (16*16*2048 = 524288 each) live in d_out scratch: only live
// between k_colstats and k_colmerge; k_out overwrites d_out at the end.

// ---------- fused reduce: q,k -> (qt,qf),(kt,kf); v -> vs ----------
__global__ __launch_bounds__(256) void k_prep(const float* __restrict__ q,
                                              const float* __restrict__ k,
                                              const float* __restrict__ v,
                                              float* __restrict__ qt,
                                              float* __restrict__ kt,
                                              float* __restrict__ qf,
                                              float* __restrict__ kf,
                                              float* __restrict__ vs) {
    __shared__ float buf[16 * DD];
    int blk = blockIdx.x;            // 0..6143
    int which = blk >> 11;           // 0=q, 1=k, 2=v
    blk &= 2047;
    const float* src = which == 0 ? q : (which == 1 ? k : v);
    int b = blk >> 7;
    int l0 = (blk & 127) << 4;
    const float4* s4 = (const float4*)(src + ((size_t)b * LL + l0) * DD);
    float4* b4 = (float4*)buf;
#pragma unroll
    for (int i = 0; i < 7; i++) b4[threadIdx.x + 256 * i] = s4[threadIdx.x + 256 * i];
    __syncthreads();
    int e = threadIdx.x & 63, g = threadIdx.x >> 6;
    if (which < 2) {
        float* t_out = which ? kt : qt;
        float* f_out = which ? kf : qf;
        float fa[7] = {0.f, 0.f, 0.f, 0.f, 0.f, 0.f, 0.f};
        for (int rr = g; rr < 16; rr += 4) {
            float s = 0.f;
#pragma unroll
            for (int r = 0; r < 7; r++) { float x = buf[rr * DD + e * 7 + r]; s += x; fa[r] += x; }
            t_out[((size_t)b * LL + l0 + rr) * EE + e] = s;
        }
        __syncthreads();
#pragma unroll
        for (int r = 0; r < 7; r++) buf[(g * 64 + e) * 7 + r] = fa[r];
        __syncthreads();
        if (g == 0) {
#pragma unroll
            for (int r = 0; r < 7; r++) {
                float s = buf[e * 7 + r] + buf[(64 + e) * 7 + r] + buf[(128 + e) * 7 + r] + buf[(192 + e) * 7 + r];
                atomicAdd(&f_out[(b * EE + e) * 7 + r], s);
            }
        }
    } else {
        float a = 0.f;
        for (int rr = g; rr < 16; rr += 4) {
#pragma unroll
            for (int r = 0; r < 7; r++) a += buf[rr * DD + e * 7 + r];
        }
        __syncthreads();
        buf[g * 64 + e] = a;
        __syncthreads();
        if (g == 0) atomicAdd(&vs[b * EE + e], buf[e] + buf[64 + e] + buf[128 + e] + buf[192 + e]);
    }
}

// ---------- feature softmax: af[b,r] = sum_p softmax_r(qf^T kf)[r,p] ----------
__global__ void k_feat(const float* __restrict__ qf, const float* __restrict__ kf,
                       float* __restrict__ af) {
    __shared__ float qs[448], ks[448], sf[49], A[49];
    int b = blockIdx.x, t = threadIdx.x;
    for (int i = t; i < 448; i += 64) { qs[i] = qf[b * 448 + i]; ks[i] = kf[b * 448 + i]; }
    __syncthreads();
    if (t < 49) {
        int r = t / 7, p = t % 7;
        float s = 0.f;
        for (int e = 0; e < 64; e++) s += qs[e * 7 + r] * ks[e * 7 + p];
        sf[t] = s;
    }
    __syncthreads();
    if (t < 7) {
        float m = -1e30f;
        for (int r = 0; r < 7; r++) m = fmaxf(m, sf[r * 7 + t]);
        float z = 0.f;
        for (int r = 0; r < 7; r++) z += __expf(sf[r * 7 + t] - m);
        float iz = 1.f / z;
        for (int r = 0; r < 7; r++) A[r * 7 + t] = __expf(sf[r * 7 + t] - m) * iz;
    }
    __syncthreads();
    if (t < 7) {
        float s = 0.f;
        for (int p = 0; p < 7; p++) s += A[t * 7 + p];
        af[b * 7 + t] = s;
    }
}

// ---------- pass A: 128x128 tile, 8x8/thread; per-column max & sumexp ----------
__global__ __launch_bounds__(256, 2) void k_colstats(const float* __restrict__ qt,
                                                     const float* __restrict__ kt,
                                                     float* __restrict__ cmp,
                                                     float* __restrict__ czp) {
    __shared__ __align__(16) float kb[128 * 68];  // cols  34.8 KB
    __shared__ __align__(16) float qb[128 * 68];  // rows  34.8 KB
    int bid = blockIdx.x;
    int b = bid >> 8, cc = (bid >> 4) & 15, rc = bid & 15;
    int c0 = cc << 7, l0 = rc << 7;
    int tid = threadIdx.x, tc = tid & 15, tr = tid >> 4;
    for (int idx = tid; idx < 2048; idx += 256) {
        int r = idx >> 4, e4 = (idx & 15) << 2;
        *(float4*)(kb + r * 68 + e4) = *(const float4*)(kt + ((size_t)(b * LL + c0 + r)) * EE + e4);
        *(float4*)(qb + r * 68 + e4) = *(const float4*)(qt + ((size_t)(b * LL + l0 + r)) * EE + e4);
    }
    __syncthreads();
    float acc[8][8];
#pragma unroll
    for (int i = 0; i < 8; i++)
#pragma unroll
        for (int j = 0; j < 8; j++) acc[i][j] = 0.f;
#pragma unroll
    for (int e = 0; e < 64; e += 4) {
        float4 qv[8], kv[8];
#pragma unroll
        for (int i = 0; i < 8; i++) qv[i] = *(const float4*)(qb + (i * 16 + tr) * 68 + e);
#pragma unroll
        for (int j = 0; j < 8; j++) kv[j] = *(const float4*)(kb + (j * 16 + tc) * 68 + e);
#pragma unroll
        for (int i = 0; i < 8; i++)
#pragma unroll
            for (int j = 0; j < 8; j++) {
                acc[i][j] += qv[i].x * kv[j].x;
                acc[i][j] += qv[i].y * kv[j].y;
                acc[i][j] += qv[i].z * kv[j].z;
                acc[i][j] += qv[i].w * kv[j].w;
            }
    }
    // per-column stats over this thread's 8 rows
    float m[8], s[8];
#pragma unroll
    for (int j = 0; j < 8; j++) {
        float m01 = fmaxf(acc[0][j], acc[1][j]), m23 = fmaxf(acc[2][j], acc[3][j]);
        float m45 = fmaxf(acc[4][j], acc[5][j]), m67 = fmaxf(acc[6][j], acc[7][j]);
        m[j] = fmaxf(fmaxf(m01, m23), fmaxf(m45, m67));
        float z = 0.f;
#pragma unroll
        for (int i = 0; i < 8; i++) z += __expf(acc[i][j] - m[j]);
        s[j] = z;
    }
    __syncthreads();
    float* mred = qb;  // [16][132]
    float* sred = kb;  // [16][132]
#pragma unroll
    for (int j = 0; j < 8; j++) {
        mred[tr * 132 + j * 16 + tc] = m[j];
        sred[tr * 132 + j * 16 + tc] = s[j];
    }
    __syncthreads();
    if (tid < 128) {
        float M = -1e30f, Z = 0.f;
        for (int g = 0; g < 16; g++) {
            float mg = mred[g * 132 + tid], sg = sred[g * 132 + tid];
            float nm = fmaxf(M, mg);
            Z = Z * __expf(M - nm) + sg * __expf(mg - nm);
            M = nm;
        }
        cmp[((size_t)(b * 16 + rc)) * LL + c0 + tid] = M;
        czp[((size_t)(b * 16 + rc)) * LL + c0 + tid] = Z;
    }
}

// ---------- merge 16 partial col stats ----------
__global__ __launch_bounds__(256) void k_colmerge(const float* __restrict__ cmp,
                                                  const float* __restrict__ czp,
                                                  float* __restrict__ cm,
                                                  float* __restrict__ cz) {
    int idx = blockIdx.x * 256 + threadIdx.x;  // 0..32767
    int b = idx >> 11, s = idx & 2047;
    float M = -1e30f, Z = 0.f;
#pragma unroll
    for (int p = 0; p < 16; p++) {
        float mg = cmp[((size_t)(b * 16 + p)) * LL + s];
        float zg = czp[((size_t)(b * 16 + p)) * LL + s];
        float nm = fmaxf(M, mg);
        Z = Z * __expf(M - nm) + zg * __expf(mg - nm);
        M = nm;
    }
    cm[idx] = M;
    cz[idx] = 1.f / Z;
}

// ---------- pass B: 128x128 tile, 8x8/thread; rowsum of normalized exp ----------
__global__ __launch_bounds__(256, 2) void k_rowsum(const float* __restrict__ qt,
                                                   const float* __restrict__ kt,
                                                   const float* __restrict__ cm,
                                                   const float* __restrict__ cz,
                                                   float* __restrict__ at) {
    __shared__ __align__(16) float kb[128 * 68];  // cols
    __shared__ __align__(16) float qb[128 * 68];  // rows
    __shared__ float mt[128], zt[128];
    int bid = blockIdx.x;
    int b = bid >> 8, rc = (bid >> 4) & 15, sc = bid & 15;
    int l0 = rc << 7, c0 = sc << 7;
    int tid = threadIdx.x, tc = tid & 15, tr = tid >> 4;
    for (int idx = tid; idx < 2048; idx += 256) {
        int r = idx >> 4, e4 = (idx & 15) << 2;
        *(float4*)(kb + r * 68 + e4) = *(const float4*)(kt + ((size_t)(b * LL + c0 + r)) * EE + e4);
        *(float4*)(qb + r * 68 + e4) = *(const float4*)(qt + ((size_t)(b * LL + l0 + r)) * EE + e4);
    }
    if (tid < 128) {
        mt[tid] = cm[b * LL + c0 + tid];
        zt[tid] = cz[b * LL + c0 + tid];
    }
    __syncthreads();
    float acc[8][8];
#pragma unroll
    for (int i = 0; i < 8; i++)
#pragma unroll
        for (int j = 0; j < 8; j++) acc[i][j] = 0.f;
#pragma unroll
    for (int e = 0; e < 64; e += 4) {
        float4 qv[8], kv[8];
#pragma unroll
        for (int i = 0; i < 8; i++) qv[i] = *(const float4*)(qb + (i * 16 + tr) * 68 + e);
#pragma unroll
        for (int j = 0; j < 8; j++) kv[j] = *(const float4*)(kb + (j * 16 + tc) * 68 + e);
#pragma unroll
        for (int i = 0; i < 8; i++)
#pragma unroll
            for (int j = 0; j < 8; j++) {
                acc[i][j] += qv[i].x * kv[j].x;
                acc[i][j] += qv[i].y * kv[j].y;
                acc[i][j] += qv[i].z * kv[j].z;
                acc[i][j] += qv[i].w * kv[j].w;
            }
    }
    float rs[8] = {0.f, 0.f, 0.f, 0.f, 0.f, 0.f, 0.f, 0.f};
#pragma unroll
    for (int j = 0; j < 8; j++) {
        int c = j * 16 + tc;
        float mc = mt[c], zc = zt[c];
#pragma unroll
        for (int i = 0; i < 8; i++) rs[i] += __expf(acc[i][j] - mc) * zc;
    }
    __syncthreads();
    float* red = qb;  // [16][132]
#pragma unroll
    for (int i = 0; i < 8; i++) red[tc * 132 + i * 16 + tr] = rs[i];
    __syncthreads();
    if (tid < 128) {
        float ssum = 0.f;
        for (int g = 0; g < 16; g++) ssum += red[g * 132 + tid];
        atomicAdd(at + (size_t)b * LL + l0 + tid, ssum);
    }
}

// ---------- per-batch softmax stats over A_tf = at[l]*af[r] ----------
__global__ __launch_bounds__(256) void k_batchstats(const float* __restrict__ at,
                                                    const float* __restrict__ af,
                                                    float* __restrict__ ms) {
    __shared__ float red[256];
    __shared__ float afs[7];
    int b = blockIdx.x, t = threadIdx.x;
    if (t < 7) afs[t] = af[b * 7 + t];
    float mx = -1e30f;
    for (int l = t; l < LL; l += 256) mx = fmaxf(mx, at[(size_t)b * LL + l]);
    red[t] = mx;
    __syncthreads();
    for (int o = 128; o > 0; o >>= 1) {
        if (t < o) red[t] = fmaxf(red[t], red[t + o]);
        __syncthreads();
    }
    float mxat = red[0];
    __syncthreads();
    float mxaf = afs[0];
#pragma unroll
    for (int r = 1; r < 7; r++) mxaf = fmaxf(mxaf, afs[r]);
    float M = mxat * mxaf;  // valid: at>0, af>0
    float s = 0.f;
    for (int l = t; l < LL; l += 256) {
        float a = at[(size_t)b * LL + l];
#pragma unroll
        for (int r = 0; r < 7; r++) s += __expf(a * afs[r] - M);
    }
    red[t] = s;
    __syncthreads();
    for (int o = 128; o > 0; o >>= 1) {
        if (t < o) red[t] += red[t + o];
        __syncthreads();
    }
    if (t == 0) { ms[b * 2] = M; ms[b * 2 + 1] = 1.f / red[0]; }
}

// ---------- output via LDS staging, coalesced float4 stores ----------
__global__ __launch_bounds__(256) void k_out(const float* __restrict__ at,
                                             const float* __restrict__ af,
                                             const float* __restrict__ vs,
                                             const float* __restrict__ ms,
                                             float* __restrict__ out) {
    __shared__ __align__(16) float sm[4 * DD];
    int row0 = blockIdx.x << 2;
    int tid = threadIdx.x;
    int g = tid >> 6, e = tid & 63;
    int row = row0 + g;
    int b = row >> 11;
    float a = at[row];
    float M = ms[b * 2], iS = ms[b * 2 + 1];
    float v = vs[b * EE + e] * iS;
#pragma unroll
    for (int r = 0; r < 7; r++) sm[g * DD + e * 7 + r] = __expf(a * af[b * 7 + r] - M) * v;
    __syncthreads();
    float4* o4 = (float4*)(out + (size_t)row0 * DD);
    const float4* s4 = (const float4*)sm;
    for (int i = tid; i < 448; i += 256) o4[i] = s4[i];
}

extern "C" void kernel_launch(void* const* d_in, const int* in_sizes, int n_in,
                              void* d_out, int out_size, void* d_ws, size_t ws_size,
                              hipStream_t stream) {
    const float* q = (const float*)d_in[0];
    const float* k = (const float*)d_in[1];
    const float* v = (const float*)d_in[2];
    float* out = (float*)d_out;
    float* ws = (float*)d_ws;

    float* qt = ws + OFF_QT;
    float* kt = ws + OFF_KT;
    float* qf = ws + OFF_QF;
    float* kf = ws + OFF_KF;
    float* vs = ws + OFF_VS;
    float* af = ws + OFF_AF;
    float* cm = ws + OFF_CM;
    float* cz = ws + OFF_CZ;
    float* at = ws + OFF_AT;
    float* ms = ws + OFF_MS;
    // cmp/czp scratch inside d_out (overwritten by k_out at the very end)
    float* cmp = out;
    float* czp = out + 524288;

    // zero the atomic accumulators: qf/kf/vs (contiguous) and at
    hipMemsetAsync(qf, 0, (7168 + 7168 + 1024) * sizeof(float), stream);
    hipMemsetAsync(at, 0, 32768 * sizeof(float), stream);

    k_prep<<<6144, 256, 0, stream>>>(q, k, v, qt, kt, qf, kf, vs);
    k_feat<<<16, 64, 0, stream>>>(qf, kf, af);
    k_colstats<<<4096, 256, 0, stream>>>(qt, kt, cmp, czp);
    k_colmerge<<<128, 256, 0, stream>>>(cmp, czp, cm, cz);
    k_rowsum<<<4096, 256, 0, stream>>>(qt, kt, cm, cz, at);
    k_batchstats<<<16, 256, 0, stream>>>(at, af, ms);
    k_out<<<8192, 256, 0, stream>>>(at, af, vs, ms, out);
}